// Round 3
// baseline (648.573 us; speedup 1.0000x reference)
//
#include <hip/hip_runtime.h>
#include <cmath>

#define BATCH 32768
#define MCH   8192     // batch chunk (4 passes) to bound workspace
#define DIM   128
#define HID   512
#define NPAD  2048     // 64 transformed dims * 32 (29 coeffs padded to 32)

typedef __attribute__((ext_vector_type(8))) _Float16 half8;
typedef __attribute__((ext_vector_type(4))) float f32x4;
typedef unsigned short u16;

__device__ __forceinline__ u16 h_bits(_Float16 h) {
  union { _Float16 h; u16 u; } v; v.h = h; return v.u;
}

// v ~= hi + lo with both f16;  |lo| <= 2^-11 |v|
__device__ __forceinline__ void split16(float f, u16& hi, u16& lo) {
  _Float16 h = (_Float16)f;
  _Float16 l = (_Float16)(f - (float)h);
  hi = h_bits(h); lo = h_bits(l);
}

__device__ __forceinline__ void async16(const void* g, void* l) {
  __builtin_amdgcn_global_load_lds(
      (const __attribute__((address_space(1))) void*)g,
      (__attribute__((address_space(3))) void*)l, 16, 0, 0);
}

// ---------------- prep kernels ----------------

__global__ __launch_bounds__(256) void prep_za_v3(const float* __restrict__ z,
                                                  u16* __restrict__ zh, u16* __restrict__ zl) {
  int id = blockIdx.x * 256 + threadIdx.x;        // < 32768*64
  int m = id >> 6, c = id & 63;
  u16 hi, lo; split16(z[(long)m * DIM + c], hi, lo);
  zh[id] = hi; zl[id] = lo;
}

__global__ __launch_bounds__(256) void prep_w12_v3(const float* __restrict__ W1, const float* __restrict__ W2,
                                                   u16* __restrict__ W1h, u16* __restrict__ W1l,
                                                   u16* __restrict__ W2h, u16* __restrict__ W2l) {
  int id = blockIdx.x * 256 + threadIdx.x;        // < 512*64 + 512*512
  if (id < 512 * 64) {
    int n = id >> 6, k = id & 63;
    u16 hi, lo; split16(W1[n * DIM + k], hi, lo); // only first 64 input cols (mask)
    W1h[id] = hi; W1l[id] = lo;
  } else {
    int j = id - 512 * 64;
    u16 hi, lo; split16(W2[j], hi, lo);
    W2h[j] = hi; W2l[j] = lo;
  }
}

__global__ __launch_bounds__(256) void prep_w3_v3(const float* __restrict__ W3, const float* __restrict__ b3,
                                                  u16* __restrict__ W3h, u16* __restrict__ W3l,
                                                  float* __restrict__ b3p) {
  int id = blockIdx.x * 256 + threadIdx.x;        // < 2048*512
  int n = id >> 9, k = id & 511;
  int g = n >> 5, kk = n & 31;                    // g: local transformed dim, kk: coeff idx
  float v = (kk < 29) ? W3[((long)((g + 64) * 29 + kk)) * HID + k] : 0.f;
  u16 hi, lo; split16(v, hi, lo);
  W3h[id] = hi; W3l[id] = lo;
  if (k == 0) b3p[n] = (kk < 29) ? b3[(g + 64) * 29 + kk] : 0.f;
}

// ------------- split-precision GEMM mainloop (128x128 tile, BK=32, 4 waves) -------------
// C = Ah*Bh + Ah*Bl + Al*Bh  (f32-accurate to ~1e-6 rel)

__device__ __forceinline__ void gemm_mainloop_split(
    const u16* __restrict__ Ah, const u16* __restrict__ Al,
    const u16* __restrict__ Bh, const u16* __restrict__ Bl, int K,
    int m0, int n0, u16* LAh, u16* LAl, u16* LBh, u16* LBl, f32x4 acc[4][4]) {
  const int t = threadIdx.x;
  const int lane = t & 63;
  const int wv = t >> 6;
  const int wr = wv >> 1, wc = wv & 1;
  const int c1 = t + 256;
  const long ar0 = (long)(m0 + (t  >> 2)) * K + (t  & 3) * 8;
  const long ar1 = (long)(m0 + (c1 >> 2)) * K + (c1 & 3) * 8;
  const long br0 = (long)(n0 + (t  >> 2)) * K + (t  & 3) * 8;
  const long br1 = (long)(n0 + (c1 >> 2)) * K + (c1 & 3) * 8;
  const int kb = (lane >> 4) * 8;
  const int arow = (lane & 15);

  for (int kt = 0; kt < K; kt += 32) {
    __syncthreads();
    async16(Ah + ar0 + kt, LAh + t  * 8);
    async16(Ah + ar1 + kt, LAh + c1 * 8);
    async16(Al + ar0 + kt, LAl + t  * 8);
    async16(Al + ar1 + kt, LAl + c1 * 8);
    async16(Bh + br0 + kt, LBh + t  * 8);
    async16(Bh + br1 + kt, LBh + c1 * 8);
    async16(Bl + br0 + kt, LBl + t  * 8);
    async16(Bl + br1 + kt, LBl + c1 * 8);
    __syncthreads();
    half8 ah[4], al[4], bh[4], bl[4];
#pragma unroll
    for (int mf = 0; mf < 4; ++mf) {
      ah[mf] = *(const half8*)(LAh + ((wr * 64 + mf * 16 + arow) * 32 + kb));
      al[mf] = *(const half8*)(LAl + ((wr * 64 + mf * 16 + arow) * 32 + kb));
    }
#pragma unroll
    for (int nf = 0; nf < 4; ++nf) {
      bh[nf] = *(const half8*)(LBh + ((wc * 64 + nf * 16 + arow) * 32 + kb));
      bl[nf] = *(const half8*)(LBl + ((wc * 64 + nf * 16 + arow) * 32 + kb));
    }
#pragma unroll
    for (int mf = 0; mf < 4; ++mf)
#pragma unroll
      for (int nf = 0; nf < 4; ++nf) {
        acc[mf][nf] = __builtin_amdgcn_mfma_f32_16x16x32_f16(ah[mf], bh[nf], acc[mf][nf], 0, 0, 0);
        acc[mf][nf] = __builtin_amdgcn_mfma_f32_16x16x32_f16(ah[mf], bl[nf], acc[mf][nf], 0, 0, 0);
        acc[mf][nf] = __builtin_amdgcn_mfma_f32_16x16x32_f16(al[mf], bh[nf], acc[mf][nf], 0, 0, 0);
      }
  }
}

// ---------------- GEMM + bias + relu -> split f16 ----------------

__global__ __launch_bounds__(256) void gemm_relu_v3(
    const u16* __restrict__ Ah, const u16* __restrict__ Al,
    const u16* __restrict__ Bh, const u16* __restrict__ Bl,
    const float* __restrict__ bias, u16* __restrict__ Ch, u16* __restrict__ Cl,
    int N, int K) {
  __shared__ __align__(16) char SMEM[32768];
  u16* LAh = (u16*)SMEM;
  u16* LAl = (u16*)(SMEM + 8192);
  u16* LBh = (u16*)(SMEM + 16384);
  u16* LBl = (u16*)(SMEM + 24576);
  const int ntiles = N >> 7;
  const int nt = blockIdx.x % ntiles;
  const int mt = blockIdx.x / ntiles;
  const int m0 = mt << 7, n0 = nt << 7;
  f32x4 zero = {0.f, 0.f, 0.f, 0.f};
  f32x4 acc[4][4];
#pragma unroll
  for (int i = 0; i < 4; ++i)
#pragma unroll
    for (int j = 0; j < 4; ++j) acc[i][j] = zero;

  gemm_mainloop_split(Ah, Al, Bh, Bl, K, m0, n0, LAh, LAl, LBh, LBl, acc);

  const int lane = threadIdx.x & 63;
  const int wv = threadIdx.x >> 6;
  const int wr = wv >> 1, wc = wv & 1;
#pragma unroll
  for (int mf = 0; mf < 4; ++mf) {
#pragma unroll
    for (int nf = 0; nf < 4; ++nf) {
      int col = n0 + wc * 64 + nf * 16 + (lane & 15);
      float bv = bias[col];
#pragma unroll
      for (int r = 0; r < 4; ++r) {
        int row = m0 + wr * 64 + mf * 16 + (lane >> 4) * 4 + r;
        float v = fmaxf(acc[mf][nf][r] + bv, 0.f);
        u16 hi, lo; split16(v, hi, lo);
        Ch[(long)row * N + col] = hi;
        Cl[(long)row * N + col] = lo;
      }
    }
  }
}

// ---------------- RQS spline (per (row, dim)) ----------------

__device__ __forceinline__ void rqs(float xin, const float uw[10], const float uh[10], const float ud9[9],
                                    float& yv, float& ldv) {
  // widths
  float mw = uw[0];
#pragma unroll
  for (int i = 1; i < 10; ++i) mw = fmaxf(mw, uw[i]);
  float ew[10]; float sw = 0.f;
#pragma unroll
  for (int i = 0; i < 10; ++i) { ew[i] = expf(uw[i] - mw); sw += ew[i]; }
  float invw = 0.99f / sw;
  float cw[11]; cw[0] = -5.f;
  {
    float run = 0.f;
#pragma unroll
    for (int i = 0; i < 10; ++i) { run += 0.001f + invw * ew[i]; cw[i + 1] = 10.f * run - 5.f; }
  }
  cw[10] = 5.f;
  // heights
  float mh = uh[0];
#pragma unroll
  for (int i = 1; i < 10; ++i) mh = fmaxf(mh, uh[i]);
  float eh[10]; float sh = 0.f;
#pragma unroll
  for (int i = 0; i < 10; ++i) { eh[i] = expf(uh[i] - mh); sh += eh[i]; }
  float invh = 0.99f / sh;
  float ch[11]; ch[0] = -5.f;
  {
    float run = 0.f;
#pragma unroll
    for (int i = 0; i < 10; ++i) { run += 0.001f + invh * eh[i]; ch[i + 1] = 10.f * run - 5.f; }
  }
  ch[10] = 5.f;
  // derivatives (softplus), padded with 1 at both ends
  float dv[11]; dv[0] = 1.f; dv[10] = 1.f;
#pragma unroll
  for (int i = 0; i < 9; ++i) {
    float x = ud9[i];
    float sp = fmaxf(x, 0.f) + log1pf(expf(-fabsf(x)));
    dv[i + 1] = 0.001f + sp;
  }

  float xc = fminf(fmaxf(xin, -5.f), 5.f);
  int b = 0;
#pragma unroll
  for (int j = 1; j <= 10; ++j) b += (cw[j] <= xc) ? 1 : 0;
  b = (b > 9) ? 9 : b;

  float wk = cw[1] - cw[0], cwk = cw[0], hk = ch[1] - ch[0], chk = ch[0], dk = dv[0], dk1 = dv[1];
#pragma unroll
  for (int j = 1; j < 10; ++j) {
    if (j == b) { wk = cw[j + 1] - cw[j]; cwk = cw[j]; hk = ch[j + 1] - ch[j]; chk = ch[j]; dk = dv[j]; dk1 = dv[j + 1]; }
  }

  float th = (xc - cwk) / wk;
  float sr = hk / wk;
  float omth = 1.f - th;
  float tm = th * omth;
  float den = sr + (dk + dk1 - 2.f * sr) * tm;
  float num = hk * (sr * th * th + dk * tm);
  float y = chk + num / den;
  float ld = logf(sr * sr * (dk1 * th * th + 2.f * sr * tm + dk * omth * omth)) - 2.f * logf(den);
  bool inside = (xin >= -5.f) && (xin <= 5.f);
  yv = inside ? y : xin;
  ldv = inside ? ld : 0.f;
  if (!isfinite(yv)) yv = 0.f;
}

// ---------------- GEMM3 fused with spline epilogue ----------------

__global__ __launch_bounds__(256) void gemm3_spline_v3(
    const u16* __restrict__ Ah, const u16* __restrict__ Al,
    const u16* __restrict__ Bh, const u16* __restrict__ Bl,
    const float* __restrict__ b3p, const float* __restrict__ z,
    float* __restrict__ xout, float* __restrict__ partial, int mbase) {
  __shared__ __align__(16) char SMEM[33024];     // staging (32KB) aliased with PT (33024B)
  u16* LAh = (u16*)SMEM;
  u16* LAl = (u16*)(SMEM + 8192);
  u16* LBh = (u16*)(SMEM + 16384);
  u16* LBl = (u16*)(SMEM + 24576);
  float (*PT)[129] = (float(*)[129])SMEM;
  const int nt = blockIdx.x & 15;
  const int mt = blockIdx.x >> 4;
  const int m0 = mt << 7, n0 = nt << 7;
  f32x4 zero = {0.f, 0.f, 0.f, 0.f};
  f32x4 acc[4][4];
#pragma unroll
  for (int i = 0; i < 4; ++i)
#pragma unroll
    for (int j = 0; j < 4; ++j) acc[i][j] = zero;

  gemm_mainloop_split(Ah, Al, Bh, Bl, HID, m0, n0, LAh, LAl, LBh, LBl, acc);

  const int t = threadIdx.x;
  const int lane = t & 63;
  const int wv = t >> 6;
  const int wr = wv >> 1, wc = wv & 1;
  const int gb = n0 >> 5;   // global transformed-dim base for this block (4 dims)

  for (int p = 0; p < 2; ++p) {
    __syncthreads();
    if (wr == p) {
#pragma unroll
      for (int mf = 0; mf < 4; ++mf)
#pragma unroll
        for (int nf = 0; nf < 4; ++nf)
#pragma unroll
          for (int r = 0; r < 4; ++r)
            PT[mf * 16 + (lane >> 4) * 4 + r][wc * 64 + nf * 16 + (lane & 15)] = acc[mf][nf][r];
    }
    __syncthreads();

    const int rl = t >> 2;          // 0..63
    const int g = t & 3;            // local dim 0..3
    const int row = p * 64 + rl;
    const int grow = mbase + m0 + row;
    const float* pr = &PT[rl][g * 32];
    const float* bb = b3p + n0 + g * 32;
    float uw[10], uh[10], ud9[9];
#pragma unroll
    for (int i = 0; i < 10; ++i) uw[i] = pr[i] + bb[i];
#pragma unroll
    for (int i = 0; i < 10; ++i) uh[i] = pr[10 + i] + bb[10 + i];
#pragma unroll
    for (int i = 0; i < 9; ++i) ud9[i] = pr[20 + i] + bb[20 + i];

    float xin = z[(long)grow * DIM + 64 + gb + g];
    float yv, ldv;
    rqs(xin, uw, uh, ud9, yv, ldv);

    xout[(long)grow * DIM + 64 + gb + g] = yv;

    float s = ldv;
    s += __shfl_down(s, 1);
    s += __shfl_down(s, 2);
    if (g == 0) partial[(long)nt * BATCH + grow] = s;
  }
}

// ---------------- pass-through copy + logdet reduce ----------------

__global__ __launch_bounds__(256) void copy_first_v3(const float* __restrict__ z, float* __restrict__ xout) {
  int id = blockIdx.x * 256 + threadIdx.x;        // < 32768*16
  int m = id >> 4, c4 = id & 15;
  const float4 v = *(const float4*)(z + (long)m * DIM + c4 * 4);
  *(float4*)(xout + (long)m * DIM + c4 * 4) = v;
}

__global__ __launch_bounds__(256) void reduce_ld_v3(const float* __restrict__ partial, float* __restrict__ ldout) {
  int row = blockIdx.x * 256 + threadIdx.x;
  float s = 0.f;
#pragma unroll
  for (int i = 0; i < 16; ++i) s += partial[(long)i * BATCH + row];
  if (!isfinite(s)) s = 0.f;
  ldout[row] = s;
}

// ---------------- launch ----------------

extern "C" void kernel_launch(void* const* d_in, const int* in_sizes, int n_in,
                              void* d_out, int out_size, void* d_ws, size_t ws_size,
                              hipStream_t stream) {
  const float* z  = (const float*)d_in[0];
  const float* W1 = (const float*)d_in[1];
  const float* b1 = (const float*)d_in[2];
  const float* W2 = (const float*)d_in[3];
  const float* b2 = (const float*)d_in[4];
  const float* W3 = (const float*)d_in[5];
  const float* b3 = (const float*)d_in[6];
  float* xout  = (float*)d_out;
  float* ldout = xout + (size_t)BATCH * DIM;

  char* ws = (char*)d_ws;
  u16* W1h = (u16*)ws;  ws += (size_t)512 * 64 * 2;
  u16* W1l = (u16*)ws;  ws += (size_t)512 * 64 * 2;
  u16* W2h = (u16*)ws;  ws += (size_t)512 * 512 * 2;
  u16* W2l = (u16*)ws;  ws += (size_t)512 * 512 * 2;
  u16* W3h = (u16*)ws;  ws += (size_t)NPAD * HID * 2;
  u16* W3l = (u16*)ws;  ws += (size_t)NPAD * HID * 2;
  float* b3p = (float*)ws; ws += (size_t)NPAD * 4;
  u16* zah = (u16*)ws;  ws += (size_t)BATCH * 64 * 2;
  u16* zal = (u16*)ws;  ws += (size_t)BATCH * 64 * 2;
  u16* h1h = (u16*)ws;  ws += (size_t)MCH * HID * 2;
  u16* h1l = (u16*)ws;  ws += (size_t)MCH * HID * 2;
  u16* h2h = (u16*)ws;  ws += (size_t)MCH * HID * 2;
  u16* h2l = (u16*)ws;  ws += (size_t)MCH * HID * 2;
  float* part = (float*)ws;  // 16 * BATCH * 4

  prep_za_v3 <<<(BATCH * 64) / 256, 256, 0, stream>>>(z, zah, zal);
  prep_w12_v3<<<(512 * 64 + 512 * 512) / 256, 256, 0, stream>>>(W1, W2, W1h, W1l, W2h, W2l);
  prep_w3_v3 <<<(NPAD * HID) / 256, 256, 0, stream>>>(W3, b3, W3h, W3l, b3p);

  for (int c = 0; c < 4; ++c) {
    const u16* zAh = zah + (size_t)c * MCH * 64;
    const u16* zAl = zal + (size_t)c * MCH * 64;
    gemm_relu_v3<<<(MCH / 128) * (512 / 128), 256, 0, stream>>>(zAh, zAl, W1h, W1l, b1, h1h, h1l, 512, 64);
    gemm_relu_v3<<<(MCH / 128) * (512 / 128), 256, 0, stream>>>(h1h, h1l, W2h, W2l, b2, h2h, h2l, 512, 512);
    gemm3_spline_v3<<<(MCH / 128) * (NPAD / 128), 256, 0, stream>>>(h2h, h2l, W3h, W3l, b3p, z, xout, part, c * MCH);
  }

  copy_first_v3<<<(BATCH * 16) / 256, 256, 0, stream>>>(z, xout);
  reduce_ld_v3<<<BATCH / 256, 256, 0, stream>>>(part, ldout);
}

// Round 4
// 403.125 us; speedup vs baseline: 1.6089x; 1.6089x over previous
//
#include <hip/hip_runtime.h>
#include <cmath>

#define BATCH 32768
#define MCH   8192     // batch chunk (4 passes) to bound workspace
#define DIM   128
#define HID   512
#define NPAD  2048     // 64 transformed dims * 32 (29 coeffs padded to 32)

typedef __attribute__((ext_vector_type(8))) _Float16 half8;
typedef __attribute__((ext_vector_type(8))) short   short8v;
typedef __attribute__((ext_vector_type(4))) float   f32x4;
typedef unsigned short u16;

// ---------------------------------------------------------------------------
// Fragment-linear (FL) layout for a [R][K] f16 operand (R%16==0, K%32==0):
//   off(r,k) = ((kt*(R/16) + (r>>4))*64 + ((r&15) | (((k&31)>>3)<<4)))*8 + (k&7)
// so a 128x32 K-tile is 8 contiguous KB, and MFMA lane l's 8 elements
// (row=l&15, k=(l>>4)*8+j) are the contiguous 16B at lane offset l*16.
// => global_load_lds stages it linearly+coalesced; ds_read_b128 at base+l*16
//    is bank-conflict-free by construction.
// ---------------------------------------------------------------------------

__device__ __forceinline__ u16 h_bits(_Float16 h) {
  union { _Float16 h; u16 u; } v; v.h = h; return v.u;
}

// v ~= hi + lo with both f16;  |lo| <= 2^-11 |v|
__device__ __forceinline__ void split16(float f, u16& hi, u16& lo) {
  _Float16 h = (_Float16)f;
  _Float16 l = (_Float16)(f - (float)h);
  hi = h_bits(h); lo = h_bits(l);
}

__device__ __forceinline__ void async16(const void* g, void* l) {
  __builtin_amdgcn_global_load_lds(
      (const __attribute__((address_space(1))) void*)g,
      (__attribute__((address_space(3))) void*)l, 16, 0, 0);
}

// ---------------- prep kernels (produce FL operands) ----------------

__global__ __launch_bounds__(256) void prep_za_v4(const float* __restrict__ z,
                                                  u16* __restrict__ zh, u16* __restrict__ zl) {
  int id = blockIdx.x * 256 + threadIdx.x;        // < 2*2048*64 lane-frags
  int l = id & 63;
  int mb = (id >> 6) & 2047;
  int kt = id >> 17;
  int r = mb * 16 + (l & 15);
  int k0 = kt * 32 + ((l >> 4) << 3);             // < 64: masked first half only
  const float* src = z + (size_t)r * DIM + k0;
  short8v H, L;
#pragma unroll
  for (int j = 0; j < 8; ++j) { u16 h, lo; split16(src[j], h, lo); H[j] = (short)h; L[j] = (short)lo; }
  *(short8v*)(zh + (size_t)id * 8) = H;
  *(short8v*)(zl + (size_t)id * 8) = L;
}

__global__ __launch_bounds__(256) void prep_w12_v4(const float* __restrict__ W1, const float* __restrict__ W2,
                                                   u16* __restrict__ W1h, u16* __restrict__ W1l,
                                                   u16* __restrict__ W2h, u16* __restrict__ W2l) {
  int id = blockIdx.x * 256 + threadIdx.x;        // < 4096 + 32768
  if (id < 4096) {                                 // W1: R=512, K=64 (first 64 cols)
    int l = id & 63, mb = (id >> 6) & 31, kt = id >> 11;
    int r = mb * 16 + (l & 15);
    int k0 = kt * 32 + ((l >> 4) << 3);
    const float* src = W1 + (size_t)r * DIM + k0;
    short8v H, L;
#pragma unroll
    for (int j = 0; j < 8; ++j) { u16 h, lo; split16(src[j], h, lo); H[j] = (short)h; L[j] = (short)lo; }
    *(short8v*)(W1h + (size_t)id * 8) = H;
    *(short8v*)(W1l + (size_t)id * 8) = L;
  } else {                                         // W2: R=512, K=512
    int id2 = id - 4096;
    int l = id2 & 63, mb = (id2 >> 6) & 31, kt = id2 >> 11;
    int r = mb * 16 + (l & 15);
    int k0 = kt * 32 + ((l >> 4) << 3);
    const float* src = W2 + (size_t)r * HID + k0;
    short8v H, L;
#pragma unroll
    for (int j = 0; j < 8; ++j) { u16 h, lo; split16(src[j], h, lo); H[j] = (short)h; L[j] = (short)lo; }
    *(short8v*)(W2h + (size_t)id2 * 8) = H;
    *(short8v*)(W2l + (size_t)id2 * 8) = L;
  }
}

__global__ __launch_bounds__(256) void prep_w3_v4(const float* __restrict__ W3,
                                                  u16* __restrict__ W3h, u16* __restrict__ W3l) {
  int id = blockIdx.x * 256 + threadIdx.x;        // < 16*128*64  (R=2048, K=512)
  int l = id & 63, mb = (id >> 6) & 127, kt = id >> 13;
  int n = mb * 16 + (l & 15);
  int k0 = kt * 32 + ((l >> 4) << 3);
  int g = n >> 5, kk = n & 31;
  short8v H, L;
  if (kk < 29) {
    const float* src = W3 + ((size_t)((g + 64) * 29 + kk)) * HID + k0;
#pragma unroll
    for (int j = 0; j < 8; ++j) { u16 h, lo; split16(src[j], h, lo); H[j] = (short)h; L[j] = (short)lo; }
  } else {
#pragma unroll
    for (int j = 0; j < 8; ++j) { H[j] = 0; L[j] = 0; }
  }
  *(short8v*)(W3h + (size_t)id * 8) = H;
  *(short8v*)(W3l + (size_t)id * 8) = L;
}

__global__ __launch_bounds__(256) void prep_b3_v4(const float* __restrict__ b3, float* __restrict__ b3p) {
  int n = blockIdx.x * 256 + threadIdx.x;          // < 2048
  int g = n >> 5, kk = n & 31;
  b3p[n] = (kk < 29) ? b3[(g + 64) * 29 + kk] : 0.f;
}

// ------------- split-precision GEMM mainloop, FL operands, LDS double-buffer -------------
// C = Ah*Bh + Ah*Bl + Al*Bh  (f32-accurate to ~1e-6 rel)
// LDS per buffer (16384 u16 = 32 KB): [Ah 4K][Al 4K][Bh 4K][Bl 4K] (u16 units)

__device__ __forceinline__ void stage_fl(const u16* __restrict__ Ah, const u16* __restrict__ Al,
                                         const u16* __restrict__ Bh, const u16* __restrict__ Bl,
                                         size_t ab, size_t bb, u16* Lb, int t) {
  async16(Ah + ab + t * 8,         Lb + t * 8);
  async16(Ah + ab + (t + 256) * 8, Lb + (t + 256) * 8);
  async16(Al + ab + t * 8,         Lb + 4096 + t * 8);
  async16(Al + ab + (t + 256) * 8, Lb + 4096 + (t + 256) * 8);
  async16(Bh + bb + t * 8,         Lb + 8192 + t * 8);
  async16(Bh + bb + (t + 256) * 8, Lb + 8192 + (t + 256) * 8);
  async16(Bl + bb + t * 8,         Lb + 12288 + t * 8);
  async16(Bl + bb + (t + 256) * 8, Lb + 12288 + (t + 256) * 8);
}

__device__ __forceinline__ void compute_fl(const u16* Lb, int lane, int wr, int wc, f32x4 acc[4][4]) {
  half8 ah[4], al[4], bh[4], bl[4];
#pragma unroll
  for (int mf = 0; mf < 4; ++mf) {
    ah[mf] = *(const half8*)(Lb +        ((wr * 4 + mf) * 64 + lane) * 8);
    al[mf] = *(const half8*)(Lb + 4096 + ((wr * 4 + mf) * 64 + lane) * 8);
  }
#pragma unroll
  for (int nf = 0; nf < 4; ++nf) {
    bh[nf] = *(const half8*)(Lb + 8192  + ((wc * 4 + nf) * 64 + lane) * 8);
    bl[nf] = *(const half8*)(Lb + 12288 + ((wc * 4 + nf) * 64 + lane) * 8);
  }
#pragma unroll
  for (int mf = 0; mf < 4; ++mf)
#pragma unroll
    for (int nf = 0; nf < 4; ++nf) {
      acc[mf][nf] = __builtin_amdgcn_mfma_f32_16x16x32_f16(ah[mf], bh[nf], acc[mf][nf], 0, 0, 0);
      acc[mf][nf] = __builtin_amdgcn_mfma_f32_16x16x32_f16(ah[mf], bl[nf], acc[mf][nf], 0, 0, 0);
      acc[mf][nf] = __builtin_amdgcn_mfma_f32_16x16x32_f16(al[mf], bh[nf], acc[mf][nf], 0, 0, 0);
    }
}

__device__ __forceinline__ void gemm_mainloop_v4(
    const u16* __restrict__ Ah, const u16* __restrict__ Al,
    const u16* __restrict__ Bh, const u16* __restrict__ Bl,
    int nkt, int a_r016, int a_rs16, int b_r016, int b_rs16,
    u16* LDS, f32x4 acc[4][4]) {
  const int t = threadIdx.x;
  const int lane = t & 63;
  const int wv = t >> 6;
  const int wr = wv >> 1, wc = wv & 1;
  u16* L0 = LDS;
  u16* L1 = LDS + 16384;

  stage_fl(Ah, Al, Bh, Bl, ((size_t)0 * a_rs16 + a_r016) * 512,
                           ((size_t)0 * b_rs16 + b_r016) * 512, L0, t);
  __syncthreads();
  for (int kt = 0; kt + 1 < nkt; ++kt) {
    u16* cur = (kt & 1) ? L1 : L0;
    u16* nxt = (kt & 1) ? L0 : L1;
    stage_fl(Ah, Al, Bh, Bl, ((size_t)(kt + 1) * a_rs16 + a_r016) * 512,
                             ((size_t)(kt + 1) * b_rs16 + b_r016) * 512, nxt, t);
    compute_fl(cur, lane, wr, wc, acc);
    __syncthreads();       // drains vmcnt for nxt; nxt loads were hidden under compute
  }
  compute_fl((nkt & 1) ? L0 : L1, lane, wr, wc, acc);
}

// ---------------- GEMM + bias + relu -> split f16 (FL output, R=MCH K=512) ----------------

__global__ __launch_bounds__(256) void gemm_relu_v4(
    const u16* __restrict__ Ah, const u16* __restrict__ Al,
    const u16* __restrict__ Bh, const u16* __restrict__ Bl,
    const float* __restrict__ bias, u16* __restrict__ Ch, u16* __restrict__ Cl,
    int nkt, int a_r016, int a_rs16) {
  __shared__ __align__(16) u16 LDS[32768];        // 64 KB: 2 x 32 KB buffers
  const int nt = blockIdx.x & 3;                  // N = 512
  const int mt = blockIdx.x >> 2;
  const int m0 = mt << 7, n0 = nt << 7;
  f32x4 zero = {0.f, 0.f, 0.f, 0.f};
  f32x4 acc[4][4];
#pragma unroll
  for (int i = 0; i < 4; ++i)
#pragma unroll
    for (int j = 0; j < 4; ++j) acc[i][j] = zero;

  gemm_mainloop_v4(Ah, Al, Bh, Bl, nkt, a_r016 + (m0 >> 4), a_rs16, n0 >> 4, 32, LDS, acc);

  const int lane = threadIdx.x & 63;
  const int wv = threadIdx.x >> 6;
  const int wr = wv >> 1, wc = wv & 1;
#pragma unroll
  for (int mf = 0; mf < 4; ++mf) {
#pragma unroll
    for (int nf = 0; nf < 4; ++nf) {
      int col = n0 + wc * 64 + nf * 16 + (lane & 15);
      float bv = bias[col];
#pragma unroll
      for (int r = 0; r < 4; ++r) {
        int row = m0 + wr * 64 + mf * 16 + (lane >> 4) * 4 + r;
        float v = fmaxf(acc[mf][nf][r] + bv, 0.f);
        u16 hi, lo; split16(v, hi, lo);
        // FL store (R=MCH, rs16=512)
        int ktO = col >> 5, mbO = row >> 4;
        int lO = (row & 15) | (((col >> 3) & 3) << 4);
        int jO = col & 7;
        size_t off = (((size_t)ktO * (MCH >> 4) + mbO) * 64 + lO) * 8 + jO;
        Ch[off] = hi; Cl[off] = lo;
      }
    }
  }
}

// ---------------- RQS spline (per (row, dim)) ----------------

__device__ __forceinline__ void rqs(float xin, const float uw[10], const float uh[10], const float ud9[9],
                                    float& yv, float& ldv) {
  float mw = uw[0];
#pragma unroll
  for (int i = 1; i < 10; ++i) mw = fmaxf(mw, uw[i]);
  float ew[10]; float sw = 0.f;
#pragma unroll
  for (int i = 0; i < 10; ++i) { ew[i] = expf(uw[i] - mw); sw += ew[i]; }
  float invw = 0.99f / sw;
  float cw[11]; cw[0] = -5.f;
  {
    float run = 0.f;
#pragma unroll
    for (int i = 0; i < 10; ++i) { run += 0.001f + invw * ew[i]; cw[i + 1] = 10.f * run - 5.f; }
  }
  cw[10] = 5.f;
  float mh = uh[0];
#pragma unroll
  for (int i = 1; i < 10; ++i) mh = fmaxf(mh, uh[i]);
  float eh[10]; float sh = 0.f;
#pragma unroll
  for (int i = 0; i < 10; ++i) { eh[i] = expf(uh[i] - mh); sh += eh[i]; }
  float invh = 0.99f / sh;
  float ch[11]; ch[0] = -5.f;
  {
    float run = 0.f;
#pragma unroll
    for (int i = 0; i < 10; ++i) { run += 0.001f + invh * eh[i]; ch[i + 1] = 10.f * run - 5.f; }
  }
  ch[10] = 5.f;
  float dv[11]; dv[0] = 1.f; dv[10] = 1.f;
#pragma unroll
  for (int i = 0; i < 9; ++i) {
    float x = ud9[i];
    float sp = fmaxf(x, 0.f) + log1pf(expf(-fabsf(x)));
    dv[i + 1] = 0.001f + sp;
  }

  float xc = fminf(fmaxf(xin, -5.f), 5.f);
  int b = 0;
#pragma unroll
  for (int j = 1; j <= 10; ++j) b += (cw[j] <= xc) ? 1 : 0;
  b = (b > 9) ? 9 : b;

  float wk = cw[1] - cw[0], cwk = cw[0], hk = ch[1] - ch[0], chk = ch[0], dk = dv[0], dk1 = dv[1];
#pragma unroll
  for (int j = 1; j < 10; ++j) {
    if (j == b) { wk = cw[j + 1] - cw[j]; cwk = cw[j]; hk = ch[j + 1] - ch[j]; chk = ch[j]; dk = dv[j]; dk1 = dv[j + 1]; }
  }

  float th = (xc - cwk) / wk;
  float sr = hk / wk;
  float omth = 1.f - th;
  float tm = th * omth;
  float den = sr + (dk + dk1 - 2.f * sr) * tm;
  float num = hk * (sr * th * th + dk * tm);
  float y = chk + num / den;
  float ld = logf(sr * sr * (dk1 * th * th + 2.f * sr * tm + dk * omth * omth)) - 2.f * logf(den);
  bool inside = (xin >= -5.f) && (xin <= 5.f);
  yv = inside ? y : xin;
  ldv = inside ? ld : 0.f;
  if (!isfinite(yv)) yv = 0.f;
}

// ---------------- GEMM3 fused with spline epilogue ----------------
// PT layout [64 rows][4 groups x 33 floats] => read/write ~conflict-free.

__global__ __launch_bounds__(256) void gemm3_spline_v4(
    const u16* __restrict__ Ah, const u16* __restrict__ Al,
    const u16* __restrict__ Bh, const u16* __restrict__ Bl,
    const float* __restrict__ b3p, const float* __restrict__ z,
    float* __restrict__ xout, float* __restrict__ partial, int mbase) {
  __shared__ __align__(16) char SMEM[65536];      // 2 x 32 KB staging, aliased with PT
  u16* LDS = (u16*)SMEM;
  float (*PT)[135] = (float(*)[135])SMEM;         // 64*135*4 = 34560 B
  const int nt = blockIdx.x & 15;
  const int mt = blockIdx.x >> 4;
  const int m0 = mt << 7, n0 = nt << 7;
  f32x4 zero = {0.f, 0.f, 0.f, 0.f};
  f32x4 acc[4][4];
#pragma unroll
  for (int i = 0; i < 4; ++i)
#pragma unroll
    for (int j = 0; j < 4; ++j) acc[i][j] = zero;

  gemm_mainloop_v4(Ah, Al, Bh, Bl, 16, m0 >> 4, MCH >> 4, n0 >> 4, NPAD >> 4, LDS, acc);

  const int t = threadIdx.x;
  const int lane = t & 63;
  const int wv = t >> 6;
  const int wr = wv >> 1, wc = wv & 1;
  const int gb = n0 >> 5;   // global transformed-dim base for this block (4 dims)

  for (int p = 0; p < 2; ++p) {
    __syncthreads();
    if (wr == p) {
#pragma unroll
      for (int mf = 0; mf < 4; ++mf)
#pragma unroll
        for (int nf = 0; nf < 4; ++nf)
#pragma unroll
          for (int r = 0; r < 4; ++r) {
            int cl = wc * 64 + nf * 16 + (lane & 15);         // local col 0..127
            PT[mf * 16 + (lane >> 4) * 4 + r][(cl >> 5) * 33 + (cl & 31)] = acc[mf][nf][r];
          }
    }
    __syncthreads();

    const int rl = t >> 2;          // 0..63
    const int g = t & 3;            // local dim 0..3
    const int row = p * 64 + rl;
    const int grow = mbase + m0 + row;
    const float* pr = &PT[rl][g * 33];
    const float* bb = b3p + n0 + g * 32;
    float uw[10], uh[10], ud9[9];
#pragma unroll
    for (int i = 0; i < 10; ++i) uw[i] = pr[i] + bb[i];
#pragma unroll
    for (int i = 0; i < 10; ++i) uh[i] = pr[10 + i] + bb[10 + i];
#pragma unroll
    for (int i = 0; i < 9; ++i) ud9[i] = pr[20 + i] + bb[20 + i];

    float xin = z[(long)grow * DIM + 64 + gb + g];
    float yv, ldv;
    rqs(xin, uw, uh, ud9, yv, ldv);

    xout[(long)grow * DIM + 64 + gb + g] = yv;

    float s = ldv;
    s += __shfl_down(s, 1);
    s += __shfl_down(s, 2);
    if (g == 0) partial[(long)nt * BATCH + grow] = s;
  }
}

// ---------------- pass-through copy + logdet reduce ----------------

__global__ __launch_bounds__(256) void copy_first_v4(const float* __restrict__ z, float* __restrict__ xout) {
  int id = blockIdx.x * 256 + threadIdx.x;        // < 32768*16
  int m = id >> 4, c4 = id & 15;
  const float4 v = *(const float4*)(z + (long)m * DIM + c4 * 4);
  *(float4*)(xout + (long)m * DIM + c4 * 4) = v;
}

__global__ __launch_bounds__(256) void reduce_ld_v4(const float* __restrict__ partial, float* __restrict__ ldout) {
  int row = blockIdx.x * 256 + threadIdx.x;
  float s = 0.f;
#pragma unroll
  for (int i = 0; i < 16; ++i) s += partial[(long)i * BATCH + row];
  if (!isfinite(s)) s = 0.f;
  ldout[row] = s;
}

// ---------------- launch ----------------

extern "C" void kernel_launch(void* const* d_in, const int* in_sizes, int n_in,
                              void* d_out, int out_size, void* d_ws, size_t ws_size,
                              hipStream_t stream) {
  const float* z  = (const float*)d_in[0];
  const float* W1 = (const float*)d_in[1];
  const float* b1 = (const float*)d_in[2];
  const float* W2 = (const float*)d_in[3];
  const float* b2 = (const float*)d_in[4];
  const float* W3 = (const float*)d_in[5];
  const float* b3 = (const float*)d_in[6];
  float* xout  = (float*)d_out;
  float* ldout = xout + (size_t)BATCH * DIM;

  char* ws = (char*)d_ws;
  u16* W1h = (u16*)ws;  ws += (size_t)512 * 64 * 2;
  u16* W1l = (u16*)ws;  ws += (size_t)512 * 64 * 2;
  u16* W2h = (u16*)ws;  ws += (size_t)512 * 512 * 2;
  u16* W2l = (u16*)ws;  ws += (size_t)512 * 512 * 2;
  u16* W3h = (u16*)ws;  ws += (size_t)NPAD * HID * 2;
  u16* W3l = (u16*)ws;  ws += (size_t)NPAD * HID * 2;
  float* b3p = (float*)ws; ws += (size_t)NPAD * 4;
  u16* zah = (u16*)ws;  ws += (size_t)BATCH * 64 * 2;
  u16* zal = (u16*)ws;  ws += (size_t)BATCH * 64 * 2;
  u16* h1h = (u16*)ws;  ws += (size_t)MCH * HID * 2;
  u16* h1l = (u16*)ws;  ws += (size_t)MCH * HID * 2;
  u16* h2h = (u16*)ws;  ws += (size_t)MCH * HID * 2;
  u16* h2l = (u16*)ws;  ws += (size_t)MCH * HID * 2;
  float* part = (float*)ws;  // 16 * BATCH * 4

  prep_za_v4 <<<(2 * 2048 * 64) / 256, 256, 0, stream>>>(z, zah, zal);
  prep_w12_v4<<<(4096 + 32768) / 256, 256, 0, stream>>>(W1, W2, W1h, W1l, W2h, W2l);
  prep_w3_v4 <<<(16 * 128 * 64) / 256, 256, 0, stream>>>(W3, W3h, W3l);
  prep_b3_v4 <<<NPAD / 256, 256, 0, stream>>>(b3, b3p);

  for (int c = 0; c < 4; ++c) {
    // GEMM1: A = za (FL over full BATCH: rs16 = 2048), K = 64 (nkt = 2)
    gemm_relu_v4<<<(MCH / 128) * 4, 256, 0, stream>>>(
        zah, zal, W1h, W1l, b1, h1h, h1l, 2, (c * MCH) >> 4, BATCH >> 4);
    // GEMM2: A = h1 (chunk-local FL: rs16 = 512), K = 512 (nkt = 16)
    gemm_relu_v4<<<(MCH / 128) * 4, 256, 0, stream>>>(
        h1h, h1l, W2h, W2l, b2, h2h, h2l, 16, 0, MCH >> 4);
    // GEMM3 + spline
    gemm3_spline_v4<<<(MCH / 128) * (NPAD / 128), 256, 0, stream>>>(
        h2h, h2l, W3h, W3l, b3p, z, xout, part, c * MCH);
  }

  copy_first_v4<<<(BATCH * 16) / 256, 256, 0, stream>>>(z, xout);
  reduce_ld_v4<<<BATCH / 256, 256, 0, stream>>>(part, ldout);
}

// Round 5
// 199.045 us; speedup vs baseline: 3.2584x; 2.0253x over previous
//
#include <hip/hip_runtime.h>
#include <cmath>

#define BATCH 32768
#define DIM   128
#define HID   512
#define NPAD  2048     // 64 transformed dims * 32 (29 coeffs padded to 32)

typedef __attribute__((ext_vector_type(8))) _Float16 half8;
typedef __attribute__((ext_vector_type(8))) short   short8v;
typedef __attribute__((ext_vector_type(4))) float   f32x4;
typedef unsigned short u16;

// ---------------------------------------------------------------------------
// Fragment-linear (FL) layout for a [R][K] f16 operand (R%16==0, K%32==0):
//   off(r,k) = ((kt*(R/16) + (r>>4))*64 + ((r&15) | (((k&31)>>3)<<4)))*8 + (k&7)
// A 128x32 K-tile is 8 contiguous KB; MFMA lane l's 8 elements are the
// contiguous 16B at lane offset l*16. => coalesced global_load_lds into
// linear LDS; ds_read_b128 at base+l*16 is bank-conflict-free.
// ---------------------------------------------------------------------------

__device__ __forceinline__ u16 f2h(float f) {
  _Float16 h = (_Float16)f;
  union { _Float16 h; u16 u; } v; v.h = h; return v.u;
}

__device__ __forceinline__ void async16(const void* g, void* l) {
  __builtin_amdgcn_global_load_lds(
      (const __attribute__((address_space(1))) void*)g,
      (__attribute__((address_space(3))) void*)l, 16, 0, 0);
}

// T1: bijective XCD-aware block swizzle (requires nwg % 8 == 0)
__device__ __forceinline__ int xcd_swz(int bid, int nwg) {
  int cpx = nwg >> 3;
  return (bid & 7) * cpx + (bid >> 3);
}

// ---------------- prep kernels (produce FL f16 operands) ----------------

__global__ __launch_bounds__(256) void prep_za_v5(const float* __restrict__ z, u16* __restrict__ zh) {
  int id = blockIdx.x * 256 + threadIdx.x;        // < 2*2048*64 lane-frags
  int l = id & 63;
  int mb = (id >> 6) & 2047;
  int kt = id >> 17;
  int r = mb * 16 + (l & 15);
  int k0 = kt * 32 + ((l >> 4) << 3);             // < 64: masked first half only
  const float* src = z + (size_t)r * DIM + k0;
  short8v H;
#pragma unroll
  for (int j = 0; j < 8; ++j) H[j] = (short)f2h(src[j]);
  *(short8v*)(zh + (size_t)id * 8) = H;
}

__global__ __launch_bounds__(256) void prep_w12_v5(const float* __restrict__ W1, const float* __restrict__ W2,
                                                   u16* __restrict__ W1h, u16* __restrict__ W2h) {
  int id = blockIdx.x * 256 + threadIdx.x;        // < 4096 + 32768
  if (id < 4096) {                                 // W1: R=512, K=64 (first 64 cols)
    int l = id & 63, mb = (id >> 6) & 31, kt = id >> 11;
    int r = mb * 16 + (l & 15);
    int k0 = kt * 32 + ((l >> 4) << 3);
    const float* src = W1 + (size_t)r * DIM + k0;
    short8v H;
#pragma unroll
    for (int j = 0; j < 8; ++j) H[j] = (short)f2h(src[j]);
    *(short8v*)(W1h + (size_t)id * 8) = H;
  } else {                                         // W2: R=512, K=512
    int id2 = id - 4096;
    int l = id2 & 63, mb = (id2 >> 6) & 31, kt = id2 >> 11;
    int r = mb * 16 + (l & 15);
    int k0 = kt * 32 + ((l >> 4) << 3);
    const float* src = W2 + (size_t)r * HID + k0;
    short8v H;
#pragma unroll
    for (int j = 0; j < 8; ++j) H[j] = (short)f2h(src[j]);
    *(short8v*)(W2h + (size_t)id2 * 8) = H;
  }
}

__global__ __launch_bounds__(256) void prep_w3_v5(const float* __restrict__ W3, u16* __restrict__ W3h) {
  int id = blockIdx.x * 256 + threadIdx.x;        // < 16*128*64  (R=2048, K=512)
  int l = id & 63, mb = (id >> 6) & 127, kt = id >> 13;
  int n = mb * 16 + (l & 15);
  int k0 = kt * 32 + ((l >> 4) << 3);
  int g = n >> 5, kk = n & 31;
  short8v H;
  if (kk < 29) {
    const float* src = W3 + ((size_t)((g + 64) * 29 + kk)) * HID + k0;
#pragma unroll
    for (int j = 0; j < 8; ++j) H[j] = (short)f2h(src[j]);
  } else {
#pragma unroll
    for (int j = 0; j < 8; ++j) H[j] = 0;
  }
  *(short8v*)(W3h + (size_t)id * 8) = H;
}

__global__ __launch_bounds__(256) void prep_b3_v5(const float* __restrict__ b3, float* __restrict__ b3p) {
  int n = blockIdx.x * 256 + threadIdx.x;          // < 2048
  int g = n >> 5, kk = n & 31;
  b3p[n] = (kk < 29) ? b3[(g + 64) * 29 + kk] : 0.f;
}

// ------------- f16 GEMM mainloop, FL operands, LDS double-buffer -------------
// LDS per buffer (8192 u16 = 16 KB): [A 4096][B 4096] (u16 units)

__device__ __forceinline__ void stage_v5(const u16* __restrict__ A, const u16* __restrict__ B,
                                         size_t ab, size_t bb, u16* Lb, int t) {
  async16(A + ab + t * 8,         Lb + t * 8);
  async16(A + ab + (t + 256) * 8, Lb + (t + 256) * 8);
  async16(B + bb + t * 8,         Lb + 4096 + t * 8);
  async16(B + bb + (t + 256) * 8, Lb + 4096 + (t + 256) * 8);
}

__device__ __forceinline__ void compute_v5(const u16* Lb, int lane, int wr, int wc, f32x4 acc[4][4]) {
  half8 a[4], b[4];
#pragma unroll
  for (int mf = 0; mf < 4; ++mf)
    a[mf] = *(const half8*)(Lb + ((wr * 4 + mf) * 64 + lane) * 8);
#pragma unroll
  for (int nf = 0; nf < 4; ++nf)
    b[nf] = *(const half8*)(Lb + 4096 + ((wc * 4 + nf) * 64 + lane) * 8);
#pragma unroll
  for (int mf = 0; mf < 4; ++mf)
#pragma unroll
    for (int nf = 0; nf < 4; ++nf)
      acc[mf][nf] = __builtin_amdgcn_mfma_f32_16x16x32_f16(a[mf], b[nf], acc[mf][nf], 0, 0, 0);
}

__device__ __forceinline__ void gemm_mainloop_v5(
    const u16* __restrict__ A, const u16* __restrict__ B,
    int nkt, int a_r016, int a_rs16, int b_r016, int b_rs16,
    u16* LDS, f32x4 acc[4][4]) {
  const int t = threadIdx.x;
  const int lane = t & 63;
  const int wv = t >> 6;
  const int wr = wv >> 1, wc = wv & 1;
  u16* L0 = LDS;
  u16* L1 = LDS + 8192;

  stage_v5(A, B, ((size_t)0 * a_rs16 + a_r016) * 512,
                 ((size_t)0 * b_rs16 + b_r016) * 512, L0, t);
  __syncthreads();
  for (int kt = 0; kt + 1 < nkt; ++kt) {
    u16* cur = (kt & 1) ? L1 : L0;
    u16* nxt = (kt & 1) ? L0 : L1;
    stage_v5(A, B, ((size_t)(kt + 1) * a_rs16 + a_r016) * 512,
                   ((size_t)(kt + 1) * b_rs16 + b_r016) * 512, nxt, t);
    compute_v5(cur, lane, wr, wc, acc);
    __syncthreads();       // next-tile loads were in flight under compute
  }
  compute_v5((nkt & 1) ? L0 : L1, lane, wr, wc, acc);
}

// ---------------- GEMM + bias + relu -> f16 (FL output, R=BATCH, K-dim N=512) ----------------

__global__ __launch_bounds__(256) void gemm_relu_v5(
    const u16* __restrict__ A, const u16* __restrict__ B,
    const float* __restrict__ bias, u16* __restrict__ C,
    int nkt, int a_rs16) {
  __shared__ __align__(16) u16 LDS[16384];        // 32 KB: 2 x 16 KB buffers
  const int bid = xcd_swz(blockIdx.x, gridDim.x);
  const int nt = bid & 3;                         // N = 512
  const int mt = bid >> 2;
  const int m0 = mt << 7, n0 = nt << 7;
  f32x4 zero = {0.f, 0.f, 0.f, 0.f};
  f32x4 acc[4][4];
#pragma unroll
  for (int i = 0; i < 4; ++i)
#pragma unroll
    for (int j = 0; j < 4; ++j) acc[i][j] = zero;

  gemm_mainloop_v5(A, B, nkt, m0 >> 4, a_rs16, n0 >> 4, 32, LDS, acc);

  const int lane = threadIdx.x & 63;
  const int wv = threadIdx.x >> 6;
  const int wr = wv >> 1, wc = wv & 1;
#pragma unroll
  for (int mf = 0; mf < 4; ++mf) {
#pragma unroll
    for (int nf = 0; nf < 4; ++nf) {
      int col = n0 + wc * 64 + nf * 16 + (lane & 15);
      float bv = bias[col];
#pragma unroll
      for (int r = 0; r < 4; ++r) {
        int row = m0 + wr * 64 + mf * 16 + (lane >> 4) * 4 + r;
        float v = fmaxf(acc[mf][nf][r] + bv, 0.f);
        // FL store (R=BATCH, rs16=2048)
        int ktO = col >> 5, mbO = row >> 4;
        int lO = (row & 15) | (((col >> 3) & 3) << 4);
        int jO = col & 7;
        size_t off = (((size_t)ktO * (BATCH >> 4) + mbO) * 64 + lO) * 8 + jO;
        C[off] = f2h(v);
      }
    }
  }
}

// ---------------- RQS spline (per (row, dim)) ----------------

__device__ __forceinline__ void rqs(float xin, const float uw[10], const float uh[10], const float ud9[9],
                                    float& yv, float& ldv) {
  float mw = uw[0];
#pragma unroll
  for (int i = 1; i < 10; ++i) mw = fmaxf(mw, uw[i]);
  float ew[10]; float sw = 0.f;
#pragma unroll
  for (int i = 0; i < 10; ++i) { ew[i] = __expf(uw[i] - mw); sw += ew[i]; }
  float invw = 0.99f / sw;
  float cw[11]; cw[0] = -5.f;
  {
    float run = 0.f;
#pragma unroll
    for (int i = 0; i < 10; ++i) { run += 0.001f + invw * ew[i]; cw[i + 1] = 10.f * run - 5.f; }
  }
  cw[10] = 5.f;
  float mh = uh[0];
#pragma unroll
  for (int i = 1; i < 10; ++i) mh = fmaxf(mh, uh[i]);
  float eh[10]; float sh = 0.f;
#pragma unroll
  for (int i = 0; i < 10; ++i) { eh[i] = __expf(uh[i] - mh); sh += eh[i]; }
  float invh = 0.99f / sh;
  float ch[11]; ch[0] = -5.f;
  {
    float run = 0.f;
#pragma unroll
    for (int i = 0; i < 10; ++i) { run += 0.001f + invh * eh[i]; ch[i + 1] = 10.f * run - 5.f; }
  }
  ch[10] = 5.f;
  float dv[11]; dv[0] = 1.f; dv[10] = 1.f;
#pragma unroll
  for (int i = 0; i < 9; ++i) {
    float x = ud9[i];
    float sp = fmaxf(x, 0.f) + __logf(1.f + __expf(-fabsf(x)));
    dv[i + 1] = 0.001f + sp;
  }

  float xc = fminf(fmaxf(xin, -5.f), 5.f);
  int b = 0;
#pragma unroll
  for (int j = 1; j <= 10; ++j) b += (cw[j] <= xc) ? 1 : 0;
  b = (b > 9) ? 9 : b;

  float wk = cw[1] - cw[0], cwk = cw[0], hk = ch[1] - ch[0], chk = ch[0], dk = dv[0], dk1 = dv[1];
#pragma unroll
  for (int j = 1; j < 10; ++j) {
    if (j == b) { wk = cw[j + 1] - cw[j]; cwk = cw[j]; hk = ch[j + 1] - ch[j]; chk = ch[j]; dk = dv[j]; dk1 = dv[j + 1]; }
  }

  float th = (xc - cwk) / wk;
  float sr = hk / wk;
  float omth = 1.f - th;
  float tm = th * omth;
  float den = sr + (dk + dk1 - 2.f * sr) * tm;
  float num = hk * (sr * th * th + dk * tm);
  float y = chk + num / den;
  float ld = __logf(sr * sr * (dk1 * th * th + 2.f * sr * tm + dk * omth * omth)) - 2.f * __logf(den);
  bool inside = (xin >= -5.f) && (xin <= 5.f);
  yv = inside ? y : xin;
  ldv = inside ? ld : 0.f;
  if (!isfinite(yv)) yv = 0.f;
}

// ---------------- GEMM3 fused with spline epilogue ----------------

__global__ __launch_bounds__(256) void gemm3_spline_v5(
    const u16* __restrict__ A, const u16* __restrict__ B,
    const float* __restrict__ b3p, const float* __restrict__ z,
    float* __restrict__ xout, float* __restrict__ partial) {
  __shared__ __align__(16) char SMEM[34816];      // 2 x 16 KB staging, aliased with PT
  u16* LDS = (u16*)SMEM;
  float (*PT)[135] = (float(*)[135])SMEM;         // 64*135*4 = 34560 B
  const int bid = xcd_swz(blockIdx.x, gridDim.x);
  const int nt = bid & 15;
  const int mt = bid >> 4;
  const int m0 = mt << 7, n0 = nt << 7;
  f32x4 zero = {0.f, 0.f, 0.f, 0.f};
  f32x4 acc[4][4];
#pragma unroll
  for (int i = 0; i < 4; ++i)
#pragma unroll
    for (int j = 0; j < 4; ++j) acc[i][j] = zero;

  gemm_mainloop_v5(A, B, 16, m0 >> 4, BATCH >> 4, n0 >> 4, NPAD >> 4, LDS, acc);

  const int t = threadIdx.x;
  const int lane = t & 63;
  const int wv = t >> 6;
  const int wr = wv >> 1, wc = wv & 1;
  const int gb = n0 >> 5;   // global transformed-dim base for this block (4 dims)

  for (int p = 0; p < 2; ++p) {
    __syncthreads();
    if (wr == p) {
#pragma unroll
      for (int mf = 0; mf < 4; ++mf)
#pragma unroll
        for (int nf = 0; nf < 4; ++nf)
#pragma unroll
          for (int r = 0; r < 4; ++r) {
            int cl = wc * 64 + nf * 16 + (lane & 15);         // local col 0..127
            PT[mf * 16 + (lane >> 4) * 4 + r][(cl >> 5) * 33 + (cl & 31)] = acc[mf][nf][r];
          }
    }
    __syncthreads();

    const int rl = t >> 2;          // 0..63
    const int g = t & 3;            // local dim 0..3
    const int row = p * 64 + rl;
    const int grow = m0 + row;
    const float* pr = &PT[rl][g * 33];
    const float* bb = b3p + n0 + g * 32;
    float uw[10], uh[10], ud9[9];
#pragma unroll
    for (int i = 0; i < 10; ++i) uw[i] = pr[i] + bb[i];
#pragma unroll
    for (int i = 0; i < 10; ++i) uh[i] = pr[10 + i] + bb[10 + i];
#pragma unroll
    for (int i = 0; i < 9; ++i) ud9[i] = pr[20 + i] + bb[20 + i];

    float xin = z[(long)grow * DIM + 64 + gb + g];
    float yv, ldv;
    rqs(xin, uw, uh, ud9, yv, ldv);

    xout[(long)grow * DIM + 64 + gb + g] = yv;

    float s = ldv;
    s += __shfl_down(s, 1);
    s += __shfl_down(s, 2);
    if (g == 0) partial[(long)nt * BATCH + grow] = s;
  }
}

// ---------------- pass-through copy + logdet reduce ----------------

__global__ __launch_bounds__(256) void copy_first_v5(const float* __restrict__ z, float* __restrict__ xout) {
  int id = blockIdx.x * 256 + threadIdx.x;        // < 32768*16
  int m = id >> 4, c4 = id & 15;
  const float4 v = *(const float4*)(z + (long)m * DIM + c4 * 4);
  *(float4*)(xout + (long)m * DIM + c4 * 4) = v;
}

__global__ __launch_bounds__(256) void reduce_ld_v5(const float* __restrict__ partial, float* __restrict__ ldout) {
  int row = blockIdx.x * 256 + threadIdx.x;
  float s = 0.f;
#pragma unroll
  for (int i = 0; i < 16; ++i) s += partial[(long)i * BATCH + row];
  if (!isfinite(s)) s = 0.f;
  ldout[row] = s;
}

// ---------------- launch ----------------

extern "C" void kernel_launch(void* const* d_in, const int* in_sizes, int n_in,
                              void* d_out, int out_size, void* d_ws, size_t ws_size,
                              hipStream_t stream) {
  const float* z  = (const float*)d_in[0];
  const float* W1 = (const float*)d_in[1];
  const float* b1 = (const float*)d_in[2];
  const float* W2 = (const float*)d_in[3];
  const float* b2 = (const float*)d_in[4];
  const float* W3 = (const float*)d_in[5];
  const float* b3 = (const float*)d_in[6];
  float* xout  = (float*)d_out;
  float* ldout = xout + (size_t)BATCH * DIM;

  char* ws = (char*)d_ws;
  u16* W1h = (u16*)ws;  ws += (size_t)512 * 64 * 2;
  u16* W2h = (u16*)ws;  ws += (size_t)512 * 512 * 2;
  u16* W3h = (u16*)ws;  ws += (size_t)NPAD * HID * 2;
  float* b3p = (float*)ws; ws += (size_t)NPAD * 4;
  // za and part alias (disjoint lifetimes: za consumed by gemm1; part written by gemm3)
  u16* zah  = (u16*)ws;
  float* part = (float*)ws; ws += (size_t)BATCH * 64 * 2;   // 4 MB (part needs 2 MB)
  u16* h1h = (u16*)ws;  ws += (size_t)BATCH * HID * 2;
  u16* h2h = (u16*)ws;  ws += (size_t)BATCH * HID * 2;

  prep_za_v5 <<<(2 * 2048 * 64) / 256, 256, 0, stream>>>(z, zah);
  prep_w12_v5<<<(4096 + 32768) / 256, 256, 0, stream>>>(W1, W2, W1h, W2h);
  prep_w3_v5 <<<(16 * 128 * 64) / 256, 256, 0, stream>>>(W3, W3h);
  prep_b3_v5 <<<NPAD / 256, 256, 0, stream>>>(b3, b3p);

  // GEMM1: A = za (R=BATCH, rs16=2048), K=64 (nkt=2)
  gemm_relu_v5<<<(BATCH / 128) * 4, 256, 0, stream>>>(zah, W1h, b1, h1h, 2, BATCH >> 4);
  // GEMM2: A = h1 (R=BATCH), K=512 (nkt=16)
  gemm_relu_v5<<<(BATCH / 128) * 4, 256, 0, stream>>>(h1h, W2h, b2, h2h, 16, BATCH >> 4);
  // GEMM3 + spline
  gemm3_spline_v5<<<(BATCH / 128) * (NPAD / 128), 256, 0, stream>>>(h2h, W3h, b3p, z, xout, part);

  copy_first_v5<<<(BATCH * 16) / 256, 256, 0, stream>>>(z, xout);
  reduce_ld_v5<<<BATCH / 256, 256, 0, stream>>>(part, ldout);
}